// Round 2
// 546.601 us; speedup vs baseline: 1.2420x; 1.2420x over previous
//
#include <hip/hip_runtime.h>

#define PLANE 1042441      // 1021*1021
#define S1 255             // h1 even-grid / h3 core spatial
#define S2 253             // h2 spatial
#define S1S1 65025
#define S2S2 64009
#define NOUT 66716224      // 8*8*1021*1021

// ws layout (floats): h1e[4161600] | h2[8193152] | h3c[4161600] | R[32] | WT[768]

// R[co*4+pc] = sum_ci relu(b3[ci]) * sum_{off-core taps for pc} w4[co][ci][jy][jx]
// WT[(co*8+ci)*12] = packed w4: [w00,w02,w20,w22, w01,w21,w10,w12, w11,0,0,0]
__global__ void k_setup(const float* __restrict__ w4, const float* __restrict__ b3_,
                        float* __restrict__ R, float* __restrict__ WT) {
  int t = threadIdx.x;
  if (t < 32) {
    int co = t >> 2, pc = t & 3;
    float s = 0.f;
    for (int ci = 0; ci < 8; ++ci) {
      float r3 = fmaxf(b3_[ci], 0.f);
      float wsum = 0.f;
      for (int jy = 0; jy < 3; ++jy)
        for (int jx = 0; jx < 3; ++jx) {
          bool cy = (pc & 2) ? (jy == 1) : (jy != 1);
          bool cx = (pc & 1) ? (jx == 1) : (jx != 1);
          if (!(cy && cx)) wsum += w4[(co * 8 + ci) * 9 + jy * 3 + jx];
        }
      s += r3 * wsum;
    }
    R[t] = s;
  }
  {
    int co = t >> 3, ci = t & 7;
    const float* w = w4 + (co * 8 + ci) * 9;
    float* d = WT + (co * 8 + ci) * 12;
    d[0] = w[0]; d[1] = w[2]; d[2] = w[6]; d[3] = w[8];
    d[4] = w[1]; d[5] = w[7]; d[6] = w[3]; d[7] = w[5];
    d[8] = w[4]; d[9] = 0.f; d[10] = 0.f; d[11] = 0.f;
  }
}

// h1e[n][co][m][t] = relu(b1 + sum x[n][ci][4m+2ky][4t+2kx]*w1), 255x255
__global__ void k_conv1(const float* __restrict__ x, const float* __restrict__ w1,
                        const float* __restrict__ b1_, float* __restrict__ h1e) {
  int t = blockIdx.x * 64 + threadIdx.x;
  int m = blockIdx.y * 4 + threadIdx.y;
  int z = blockIdx.z;                 // n*8+co
  if (t >= S1 || m >= S1) return;
  int n = z >> 3, co = z & 7;
  float acc = b1_[co];
  const float* wp = w1 + co * 27;
  const float* xn = x + (size_t)n * 3 * PLANE;
#pragma unroll
  for (int ci = 0; ci < 3; ++ci) {
    const float* xc = xn + ci * PLANE;
#pragma unroll
    for (int ky = 0; ky < 3; ++ky) {
      const float* xr = xc + (4 * m + 2 * ky) * 1021 + 4 * t;
#pragma unroll
      for (int kx = 0; kx < 3; ++kx)
        acc = fmaf(xr[2 * kx], wp[(ci * 3 + ky) * 3 + kx], acc);
    }
  }
  h1e[((size_t)z * S1 + m) * S1 + t] = fmaxf(acc, 0.f);
}

// h2: 4 pixels (v) x 4 co per thread. 16 independent accumulators.
__global__ __launch_bounds__(256) void k_conv2(const float* __restrict__ h1e,
    const float* __restrict__ w2, const float* __restrict__ b2_, float* __restrict__ h2) {
  int v0 = threadIdx.x * 4;                  // 0..252
  int u = blockIdx.y * 4 + threadIdx.y;
  int zb = blockIdx.z;                       // n*4 + cog'
  int n = zb >> 2, cog = (zb & 3) * 4;
  if (u >= S2) return;
  float acc[4][4];
#pragma unroll
  for (int cc = 0; cc < 4; ++cc) {
    float b = b2_[cog + cc];
#pragma unroll
    for (int p = 0; p < 4; ++p) acc[cc][p] = b;
  }
  const float* hn = h1e + (size_t)n * 8 * S1S1;
  for (int ci = 0; ci < 8; ++ci) {
    const float* hc = hn + ci * S1S1;
#pragma unroll
    for (int ky = 0; ky < 3; ++ky) {
      const float* hr = hc + (u + ky) * S1 + v0;
      float rr[6];
#pragma unroll
      for (int q = 0; q < 6; ++q) rr[q] = hr[q];  // may read past row end: only feeds invalid outputs
#pragma unroll
      for (int cc = 0; cc < 4; ++cc) {
        const float* w = w2 + (cog + cc) * 72 + ci * 9 + ky * 3;
        float w0 = w[0], w1 = w[1], w2v = w[2];
#pragma unroll
        for (int p = 0; p < 4; ++p)
          acc[cc][p] = fmaf(rr[p], w0, fmaf(rr[p + 1], w1, fmaf(rr[p + 2], w2v, acc[cc][p])));
      }
    }
  }
#pragma unroll
  for (int cc = 0; cc < 4; ++cc) {
    float* op = h2 + ((size_t)(n * 16 + cog + cc) * S2 + u) * S2 + v0;
#pragma unroll
    for (int p = 0; p < 4; ++p)
      if (v0 + p < S2) op[p] = fmaxf(acc[cc][p], 0.f);
  }
}

// h3core: 4 pixels (r) x 4 co per thread.
__global__ __launch_bounds__(256) void k_deconv3(const float* __restrict__ h2,
    const float* __restrict__ w3, const float* __restrict__ b3_, float* __restrict__ h3c) {
  int r0 = threadIdx.x * 4;                  // 0..252
  int q = blockIdx.y * 4 + threadIdx.y;
  int zb = blockIdx.z;                       // n*2 + g
  int n = zb >> 1, cog = (zb & 1) * 4;
  if (q >= S1) return;
  float acc[4][4];
#pragma unroll
  for (int cc = 0; cc < 4; ++cc) {
    float b = b3_[cog + cc];
#pragma unroll
    for (int p = 0; p < 4; ++p) acc[cc][p] = b;
  }
  const float* hn = h2 + (size_t)n * 16 * S2S2;
  bool inner = (r0 >= 4 && r0 <= 248);
  for (int ci = 0; ci < 16; ++ci) {
    const float* hc = hn + ci * S2S2;
#pragma unroll
    for (int jy = 0; jy < 3; ++jy) {
      int a = q - jy;
      if ((unsigned)a > 252u) continue;
      const float* hr = hc + a * S2 + (r0 - 2);
      float rr[6];
      if (inner) {
#pragma unroll
        for (int q2 = 0; q2 < 6; ++q2) rr[q2] = hr[q2];
      } else {
#pragma unroll
        for (int q2 = 0; q2 < 6; ++q2) {
          int col = r0 - 2 + q2;
          rr[q2] = ((unsigned)col <= 252u) ? hr[q2] : 0.f;
        }
      }
#pragma unroll
      for (int cc = 0; cc < 4; ++cc) {
        const float* w = w3 + ((cog + cc) * 16 + ci) * 9 + jy * 3;
        float w0 = w[0], w1 = w[1], w2v = w[2];
        // b = r0+p-jx -> rr[p-jx+2]
#pragma unroll
        for (int p = 0; p < 4; ++p)
          acc[cc][p] = fmaf(rr[p + 2], w0, fmaf(rr[p + 1], w1, fmaf(rr[p], w2v, acc[cc][p])));
      }
    }
  }
#pragma unroll
  for (int cc = 0; cc < 4; ++cc)
#pragma unroll
    for (int p = 0; p < 4; ++p)
      if (r0 + p < S1)
        h3c[((size_t)(n * 8 + cog + cc) * S1 + q) * S1 + r0 + p] = fmaxf(acc[cc][p], 0.f);
}

// General (border) per-element output value.
__device__ __forceinline__ float general_val(unsigned idx, const float* __restrict__ h3c,
    const float* __restrict__ w4, const float* __restrict__ b4_, const float* __restrict__ b3_) {
  unsigned z = idx / PLANE;
  unsigned rem = idx - z * PLANE;
  unsigned y = rem / 1021u;
  unsigned x = rem - y * 1021u;
  int co = z & 7;
  float acc = b4_[co];
  if ((y | x) & 1u) return acc;
  int py = y >> 1, px = x >> 1;
  const float* hn = h3c + (size_t)(z >> 3) * 8 * S1S1;
  const float* wp = w4 + co * 72;
  for (int ci = 0; ci < 8; ++ci) {
    float r3 = fmaxf(b3_[ci], 0.f);
    const float* hcc = hn + ci * S1S1;
#pragma unroll
    for (int jy = 0; jy < 3; ++jy) {
      int a = py - jy;
#pragma unroll
      for (int jx = 0; jx < 3; ++jx) {
        int b = px - jx;
        float h;
        if ((unsigned)a > 508u || (unsigned)b > 508u) h = 0.f;
        else if (((a | b) & 1) == 0) h = hcc[(a >> 1) * S1 + (b >> 1)];
        else h = r3;
        acc = fmaf(h, wp[ci * 9 + jy * 3 + jx], acc);
      }
    }
  }
  return acc;
}

// Row-pair kernel: block = (even row ye=2*bx, odd row ye+1) of plane z.
// No divisions, y-parity is block-uniform, no chunk crosses a row.
// Fast path: threads t=1..253 write x=4t..4t+3 (px 2..507, all taps in-range so
// the R[] off-core constant is exact). t=0/254/255 even-row coverage -> border kernel.
__global__ __launch_bounds__(256) void k_out_rows(const float* __restrict__ h3c,
    const float* __restrict__ b4_, const float* __restrict__ R,
    const float* __restrict__ WT, float* __restrict__ out) {
  int t = threadIdx.x;
  int ye = blockIdx.x * 2;                   // even row, 0..1020
  int z = blockIdx.y;                        // n*8+co
  int co = z & 7;
  float b4f = b4_[co];
  float* orow = out + (size_t)z * PLANE + (size_t)ye * 1021u;

  // odd row ye+1: pure constant
  if (ye < 1020) {
    float* orow1 = orow + 1021;
    if (t < 255) *(float4*)(orow1 + 4 * t) = make_float4(b4f, b4f, b4f, b4f);
    else orow1[1020] = b4f;
  }

  // even row: interior only (border kernel covers ye in {0,2,1018,1020},
  // and x in {0..3, 1016..1020} of other even rows)
  if (ye < 4 || ye > 1016) return;
  if (t == 0 || t >= 254) return;
  unsigned py = (unsigned)ye >> 1;
  const float* hn = h3c + (size_t)(z >> 3) * 8 * S1S1;
  const float* wt = WT + co * 96;
  int col0 = t - 1;                          // cols col0, col0+1 feed px=2t (even), px=2t+1 (odd)
  float vE = 0.f, vO = 0.f, rE, rO;
  if ((py & 1u) == 0) {
    unsigned i = py >> 1;                    // rows i-1, i of h3c
    const float* hp = hn + (i - 1) * S1 + col0;
#pragma unroll
    for (int ci = 0; ci < 8; ++ci) {
      const float* p = hp + ci * S1S1;
      float m00 = p[0], m01 = p[1], m10 = p[S1], m11 = p[S1 + 1];
      float4 A = *(const float4*)(wt + ci * 12);
      float4 B = *(const float4*)(wt + ci * 12 + 4);
      vE = fmaf(m11, A.x, fmaf(m10, A.y, fmaf(m01, A.z, fmaf(m00, A.w, vE))));
      vO = fmaf(m11, B.x, fmaf(m01, B.y, vO));
    }
    rE = b4f + R[co * 4 + 0] + vE;
    rO = b4f + R[co * 4 + 1] + vO;
  } else {
    unsigned a = py >> 1;                    // single row a of h3c
    const float* hp = hn + a * S1 + col0;
#pragma unroll
    for (int ci = 0; ci < 8; ++ci) {
      const float* p = hp + ci * S1S1;
      float n0 = p[0], n1 = p[1];
      float4 B = *(const float4*)(wt + ci * 12 + 4);
      float w11 = wt[ci * 12 + 8];
      vE = fmaf(n1, B.z, fmaf(n0, B.w, vE));
      vO = fmaf(n1, w11, vO);
    }
    rE = b4f + R[co * 4 + 2] + vE;
    rO = b4f + R[co * 4 + 3] + vO;
  }
  *(float4*)(orow + 4 * t) = make_float4(rE, b4f, rO, b4f);
}

// Border kernel: even-row x-borders (x in {0,1,2,3} u {1016..1020}, y=4..1016 even: 507 rows)
// and the 4 even border rows (y in {0,2,1018,1020}) in full. ~2% of output.
__global__ __launch_bounds__(256) void k_out_border(const float* __restrict__ h3c,
    const float* __restrict__ w4, const float* __restrict__ b4_,
    const float* __restrict__ b3_, float* __restrict__ out) {
  int z = blockIdx.y;
  unsigned y, x;
  if (blockIdx.x < 18) {                     // x-border: 507*9 = 4563 elements
    unsigned e = blockIdx.x * 256 + threadIdx.x;
    if (e >= 507u * 9u) return;
    unsigned r = e / 9u, c = e - r * 9u;
    y = 4u + 2u * r;
    x = (c < 4u) ? c : (1012u + c);          // c=4..8 -> 1016..1020
  } else {                                   // y-border rows: 4*1021 = 4084 elements
    unsigned e2 = (blockIdx.x - 18) * 256 + threadIdx.x;
    if (e2 >= 4u * 1021u) return;
    unsigned rr = e2 / 1021u;
    y = (rr < 2u) ? 2u * rr : (1014u + 2u * rr);   // 0,2,1018,1020
    x = e2 - rr * 1021u;
  }
  unsigned idx = (unsigned)z * PLANE + y * 1021u + x;
  out[idx] = general_val(idx, h3c, w4, b4_, b3_);
}

extern "C" void kernel_launch(void* const* d_in, const int* in_sizes, int n_in,
                              void* d_out, int out_size, void* d_ws, size_t ws_size,
                              hipStream_t stream) {
  const float* x   = (const float*)d_in[0];
  const float* w1  = (const float*)d_in[1];
  const float* b1_ = (const float*)d_in[2];
  const float* w2  = (const float*)d_in[3];
  const float* b2_ = (const float*)d_in[4];
  const float* w3  = (const float*)d_in[5];
  const float* b3_ = (const float*)d_in[6];
  const float* w4  = (const float*)d_in[7];
  const float* b4_ = (const float*)d_in[8];
  float* out = (float*)d_out;

  float* h1e = (float*)d_ws;
  float* h2  = h1e + (size_t)8 * 8 * S1S1;
  float* h3c = h2 + (size_t)8 * 16 * S2S2;
  float* R   = h3c + (size_t)8 * 8 * S1S1;
  float* WT  = R + 32;

  dim3 blk(64, 4, 1);
  k_setup<<<1, 64, 0, stream>>>(w4, b3_, R, WT);
  k_conv1<<<dim3(4, 64, 64), blk, 0, stream>>>(x, w1, b1_, h1e);
  k_conv2<<<dim3(1, 64, 32), blk, 0, stream>>>(h1e, w2, b2_, h2);
  k_deconv3<<<dim3(1, 64, 16), blk, 0, stream>>>(h2, w3, b3_, h3c);
  k_out_rows<<<dim3(511, 64), 256, 0, stream>>>(h3c, b4_, R, WT, out);
  k_out_border<<<dim3(34, 64), 256, 0, stream>>>(h3c, w4, b4_, b3_, out);
}

// Round 3
// 481.433 us; speedup vs baseline: 1.4101x; 1.1354x over previous
//
#include <hip/hip_runtime.h>

#define PLANE 1042441      // 1021*1021
#define S1 255             // h1 even-grid / h3 core spatial
#define S2 253             // h2 spatial
#define S1S1 65025
#define S2S2 64009
#define NOUT 66716224      // 8*8*1021*1021

// ws layout (floats): h1e[4161600] | h2[8193152] | h3c[4161600] | R[32] | WT[768]

// R[co*4+pc] = sum_ci relu(b3[ci]) * sum_{off-core taps for pc} w4[co][ci][jy][jx]
// WT[(co*8+ci)*12] = packed w4: [w00,w02,w20,w22, w01,w21,w10,w12, w11,0,0,0]
__global__ void k_setup(const float* __restrict__ w4, const float* __restrict__ b3_,
                        float* __restrict__ R, float* __restrict__ WT) {
  int t = threadIdx.x;
  if (t < 32) {
    int co = t >> 2, pc = t & 3;
    float s = 0.f;
    for (int ci = 0; ci < 8; ++ci) {
      float r3 = fmaxf(b3_[ci], 0.f);
      float wsum = 0.f;
      for (int jy = 0; jy < 3; ++jy)
        for (int jx = 0; jx < 3; ++jx) {
          bool cy = (pc & 2) ? (jy == 1) : (jy != 1);
          bool cx = (pc & 1) ? (jx == 1) : (jx != 1);
          if (!(cy && cx)) wsum += w4[(co * 8 + ci) * 9 + jy * 3 + jx];
        }
      s += r3 * wsum;
    }
    R[t] = s;
  }
  {
    int co = t >> 3, ci = t & 7;
    const float* w = w4 + (co * 8 + ci) * 9;
    float* d = WT + (co * 8 + ci) * 12;
    d[0] = w[0]; d[1] = w[2]; d[2] = w[6]; d[3] = w[8];
    d[4] = w[1]; d[5] = w[7]; d[6] = w[3]; d[7] = w[5];
    d[8] = w[4]; d[9] = 0.f; d[10] = 0.f; d[11] = 0.f;
  }
}

// conv1 rewrite: each thread computes 4 outputs (t0..t0+3) x 4 co (cog..cog+3).
// Per (ci,ky): 9 even-column loads shared by all 16 outputs (vs 27 loads/output before).
// x read multiplicity over co drops 8x -> 2x (two cog groups).
__global__ __launch_bounds__(256) void k_conv1(const float* __restrict__ x,
    const float* __restrict__ w1, const float* __restrict__ b1_, float* __restrict__ h1e) {
  int tx = threadIdx.x;                      // 0..63
  int t0 = tx * 4;                           // output col base, 0..252
  int m = blockIdx.y * 4 + threadIdx.y;      // output row
  if (m >= S1) return;                       // wave-uniform (ty fixed per wave)
  int zb = blockIdx.z;                       // n*2 + g
  int n = zb >> 1, cog = (zb & 1) * 4;

  float acc[4][4];
#pragma unroll
  for (int cc = 0; cc < 4; ++cc) {
    float b = b1_[cog + cc];
#pragma unroll
    for (int p = 0; p < 4; ++p) acc[cc][p] = b;
  }

  const float* xn = x + (size_t)n * 3 * PLANE;
  int b0 = 4 * t0;                           // x col base = 16*tx, <= 1008
  // v[7]/v[8] only feed output p=3; for tx==63 p=3 is masked -> clamp cols in-bounds.
  int o7 = b0 + 14 <= 1020 ? b0 + 14 : 1020;
  int o8 = b0 + 16 <= 1020 ? b0 + 16 : 1020;

#pragma unroll
  for (int ci = 0; ci < 3; ++ci) {
#pragma unroll
    for (int ky = 0; ky < 3; ++ky) {
      const float* xr = xn + ci * PLANE + (size_t)(4 * m + 2 * ky) * 1021u;
      float v[9];
      v[0] = xr[b0];      v[1] = xr[b0 + 2];  v[2] = xr[b0 + 4];
      v[3] = xr[b0 + 6];  v[4] = xr[b0 + 8];  v[5] = xr[b0 + 10];
      v[6] = xr[b0 + 12]; v[7] = xr[o7];      v[8] = xr[o8];
#pragma unroll
      for (int cc = 0; cc < 4; ++cc) {
        const float* w = w1 + (cog + cc) * 27 + ci * 9 + ky * 3;
        float w0 = w[0], w1v = w[1], w2v = w[2];
        // output t0+p, kx tap -> x col b0+4p+2kx -> v[2p+kx]
#pragma unroll
        for (int p = 0; p < 4; ++p)
          acc[cc][p] = fmaf(v[2 * p], w0, fmaf(v[2 * p + 1], w1v, fmaf(v[2 * p + 2], w2v, acc[cc][p])));
      }
    }
  }

#pragma unroll
  for (int cc = 0; cc < 4; ++cc) {
    float* op = h1e + ((size_t)(n * 8 + cog + cc) * S1 + m) * S1 + t0;
#pragma unroll
    for (int p = 0; p < 4; ++p)
      if (t0 + p < S1) op[p] = fmaxf(acc[cc][p], 0.f);
  }
}

// h2: 4 pixels (v) x 4 co per thread. 16 independent accumulators.
__global__ __launch_bounds__(256) void k_conv2(const float* __restrict__ h1e,
    const float* __restrict__ w2, const float* __restrict__ b2_, float* __restrict__ h2) {
  int v0 = threadIdx.x * 4;                  // 0..252
  int u = blockIdx.y * 4 + threadIdx.y;
  int zb = blockIdx.z;                       // n*4 + cog'
  int n = zb >> 2, cog = (zb & 3) * 4;
  if (u >= S2) return;
  float acc[4][4];
#pragma unroll
  for (int cc = 0; cc < 4; ++cc) {
    float b = b2_[cog + cc];
#pragma unroll
    for (int p = 0; p < 4; ++p) acc[cc][p] = b;
  }
  const float* hn = h1e + (size_t)n * 8 * S1S1;
  for (int ci = 0; ci < 8; ++ci) {
    const float* hc = hn + ci * S1S1;
#pragma unroll
    for (int ky = 0; ky < 3; ++ky) {
      const float* hr = hc + (u + ky) * S1 + v0;
      float rr[6];
#pragma unroll
      for (int q = 0; q < 6; ++q) rr[q] = hr[q];  // may read past row end: only feeds invalid outputs
#pragma unroll
      for (int cc = 0; cc < 4; ++cc) {
        const float* w = w2 + (cog + cc) * 72 + ci * 9 + ky * 3;
        float w0 = w[0], w1 = w[1], w2v = w[2];
#pragma unroll
        for (int p = 0; p < 4; ++p)
          acc[cc][p] = fmaf(rr[p], w0, fmaf(rr[p + 1], w1, fmaf(rr[p + 2], w2v, acc[cc][p])));
      }
    }
  }
#pragma unroll
  for (int cc = 0; cc < 4; ++cc) {
    float* op = h2 + ((size_t)(n * 16 + cog + cc) * S2 + u) * S2 + v0;
#pragma unroll
    for (int p = 0; p < 4; ++p)
      if (v0 + p < S2) op[p] = fmaxf(acc[cc][p], 0.f);
  }
}

// h3core: 4 pixels (r) x 4 co per thread.
__global__ __launch_bounds__(256) void k_deconv3(const float* __restrict__ h2,
    const float* __restrict__ w3, const float* __restrict__ b3_, float* __restrict__ h3c) {
  int r0 = threadIdx.x * 4;                  // 0..252
  int q = blockIdx.y * 4 + threadIdx.y;
  int zb = blockIdx.z;                       // n*2 + g
  int n = zb >> 1, cog = (zb & 1) * 4;
  if (q >= S1) return;
  float acc[4][4];
#pragma unroll
  for (int cc = 0; cc < 4; ++cc) {
    float b = b3_[cog + cc];
#pragma unroll
    for (int p = 0; p < 4; ++p) acc[cc][p] = b;
  }
  const float* hn = h2 + (size_t)n * 16 * S2S2;
  bool inner = (r0 >= 4 && r0 <= 248);
  for (int ci = 0; ci < 16; ++ci) {
    const float* hc = hn + ci * S2S2;
#pragma unroll
    for (int jy = 0; jy < 3; ++jy) {
      int a = q - jy;
      if ((unsigned)a > 252u) continue;
      const float* hr = hc + a * S2 + (r0 - 2);
      float rr[6];
      if (inner) {
#pragma unroll
        for (int q2 = 0; q2 < 6; ++q2) rr[q2] = hr[q2];
      } else {
#pragma unroll
        for (int q2 = 0; q2 < 6; ++q2) {
          int col = r0 - 2 + q2;
          rr[q2] = ((unsigned)col <= 252u) ? hr[q2] : 0.f;
        }
      }
#pragma unroll
      for (int cc = 0; cc < 4; ++cc) {
        const float* w = w3 + ((cog + cc) * 16 + ci) * 9 + jy * 3;
        float w0 = w[0], w1 = w[1], w2v = w[2];
        // b = r0+p-jx -> rr[p-jx+2]
#pragma unroll
        for (int p = 0; p < 4; ++p)
          acc[cc][p] = fmaf(rr[p + 2], w0, fmaf(rr[p + 1], w1, fmaf(rr[p], w2v, acc[cc][p])));
      }
    }
  }
#pragma unroll
  for (int cc = 0; cc < 4; ++cc)
#pragma unroll
    for (int p = 0; p < 4; ++p)
      if (r0 + p < S1)
        h3c[((size_t)(n * 8 + cog + cc) * S1 + q) * S1 + r0 + p] = fmaxf(acc[cc][p], 0.f);
}

// General (border) per-element output value.
__device__ __forceinline__ float general_val(unsigned idx, const float* __restrict__ h3c,
    const float* __restrict__ w4, const float* __restrict__ b4_, const float* __restrict__ b3_) {
  unsigned z = idx / PLANE;
  unsigned rem = idx - z * PLANE;
  unsigned y = rem / 1021u;
  unsigned x = rem - y * 1021u;
  int co = z & 7;
  float acc = b4_[co];
  if ((y | x) & 1u) return acc;
  int py = y >> 1, px = x >> 1;
  const float* hn = h3c + (size_t)(z >> 3) * 8 * S1S1;
  const float* wp = w4 + co * 72;
  for (int ci = 0; ci < 8; ++ci) {
    float r3 = fmaxf(b3_[ci], 0.f);
    const float* hcc = hn + ci * S1S1;
#pragma unroll
    for (int jy = 0; jy < 3; ++jy) {
      int a = py - jy;
#pragma unroll
      for (int jx = 0; jx < 3; ++jx) {
        int b = px - jx;
        float h;
        if ((unsigned)a > 508u || (unsigned)b > 508u) h = 0.f;
        else if (((a | b) & 1) == 0) h = hcc[(a >> 1) * S1 + (b >> 1)];
        else h = r3;
        acc = fmaf(h, wp[ci * 9 + jy * 3 + jx], acc);
      }
    }
  }
  return acc;
}

// Row-pair kernel: block = (even row ye=2*bx, odd row ye+1) of plane z.
// No divisions, y-parity is block-uniform, no chunk crosses a row.
// Fast path: threads t=1..253 write x=4t..4t+3 (px 2..507, all taps in-range so
// the R[] off-core constant is exact). t=0/254/255 even-row coverage -> border kernel.
__global__ __launch_bounds__(256) void k_out_rows(const float* __restrict__ h3c,
    const float* __restrict__ b4_, const float* __restrict__ R,
    const float* __restrict__ WT, float* __restrict__ out) {
  int t = threadIdx.x;
  int ye = blockIdx.x * 2;                   // even row, 0..1020
  int z = blockIdx.y;                        // n*8+co
  int co = z & 7;
  float b4f = b4_[co];
  float* orow = out + (size_t)z * PLANE + (size_t)ye * 1021u;

  // odd row ye+1: pure constant
  if (ye < 1020) {
    float* orow1 = orow + 1021;
    if (t < 255) *(float4*)(orow1 + 4 * t) = make_float4(b4f, b4f, b4f, b4f);
    else orow1[1020] = b4f;
  }

  // even row: interior only (border kernel covers ye in {0,2,1018,1020},
  // and x in {0..3, 1016..1020} of other even rows)
  if (ye < 4 || ye > 1016) return;
  if (t == 0 || t >= 254) return;
  unsigned py = (unsigned)ye >> 1;
  const float* hn = h3c + (size_t)(z >> 3) * 8 * S1S1;
  const float* wt = WT + co * 96;
  int col0 = t - 1;                          // cols col0, col0+1 feed px=2t (even), px=2t+1 (odd)
  float vE = 0.f, vO = 0.f, rE, rO;
  if ((py & 1u) == 0) {
    unsigned i = py >> 1;                    // rows i-1, i of h3c
    const float* hp = hn + (i - 1) * S1 + col0;
#pragma unroll
    for (int ci = 0; ci < 8; ++ci) {
      const float* p = hp + ci * S1S1;
      float m00 = p[0], m01 = p[1], m10 = p[S1], m11 = p[S1 + 1];
      float4 A = *(const float4*)(wt + ci * 12);
      float4 B = *(const float4*)(wt + ci * 12 + 4);
      vE = fmaf(m11, A.x, fmaf(m10, A.y, fmaf(m01, A.z, fmaf(m00, A.w, vE))));
      vO = fmaf(m11, B.x, fmaf(m01, B.y, vO));
    }
    rE = b4f + R[co * 4 + 0] + vE;
    rO = b4f + R[co * 4 + 1] + vO;
  } else {
    unsigned a = py >> 1;                    // single row a of h3c
    const float* hp = hn + a * S1 + col0;
#pragma unroll
    for (int ci = 0; ci < 8; ++ci) {
      const float* p = hp + ci * S1S1;
      float n0 = p[0], n1 = p[1];
      float4 B = *(const float4*)(wt + ci * 12 + 4);
      float w11 = wt[ci * 12 + 8];
      vE = fmaf(n1, B.z, fmaf(n0, B.w, vE));
      vO = fmaf(n1, w11, vO);
    }
    rE = b4f + R[co * 4 + 2] + vE;
    rO = b4f + R[co * 4 + 3] + vO;
  }
  *(float4*)(orow + 4 * t) = make_float4(rE, b4f, rO, b4f);
}

// Border kernel: even-row x-borders (x in {0,1,2,3} u {1016..1020}, y=4..1016 even: 507 rows)
// and the 4 even border rows (y in {0,2,1018,1020}) in full. ~2% of output.
__global__ __launch_bounds__(256) void k_out_border(const float* __restrict__ h3c,
    const float* __restrict__ w4, const float* __restrict__ b4_,
    const float* __restrict__ b3_, float* __restrict__ out) {
  int z = blockIdx.y;
  unsigned y, x;
  if (blockIdx.x < 18) {                     // x-border: 507*9 = 4563 elements
    unsigned e = blockIdx.x * 256 + threadIdx.x;
    if (e >= 507u * 9u) return;
    unsigned r = e / 9u, c = e - r * 9u;
    y = 4u + 2u * r;
    x = (c < 4u) ? c : (1012u + c);          // c=4..8 -> 1016..1020
  } else {                                   // y-border rows: 4*1021 = 4084 elements
    unsigned e2 = (blockIdx.x - 18) * 256 + threadIdx.x;
    if (e2 >= 4u * 1021u) return;
    unsigned rr = e2 / 1021u;
    y = (rr < 2u) ? 2u * rr : (1014u + 2u * rr);   // 0,2,1018,1020
    x = e2 - rr * 1021u;
  }
  unsigned idx = (unsigned)z * PLANE + y * 1021u + x;
  out[idx] = general_val(idx, h3c, w4, b4_, b3_);
}

extern "C" void kernel_launch(void* const* d_in, const int* in_sizes, int n_in,
                              void* d_out, int out_size, void* d_ws, size_t ws_size,
                              hipStream_t stream) {
  const float* x   = (const float*)d_in[0];
  const float* w1  = (const float*)d_in[1];
  const float* b1_ = (const float*)d_in[2];
  const float* w2  = (const float*)d_in[3];
  const float* b2_ = (const float*)d_in[4];
  const float* w3  = (const float*)d_in[5];
  const float* b3_ = (const float*)d_in[6];
  const float* w4  = (const float*)d_in[7];
  const float* b4_ = (const float*)d_in[8];
  float* out = (float*)d_out;

  float* h1e = (float*)d_ws;
  float* h2  = h1e + (size_t)8 * 8 * S1S1;
  float* h3c = h2 + (size_t)8 * 16 * S2S2;
  float* R   = h3c + (size_t)8 * 8 * S1S1;
  float* WT  = R + 32;

  k_setup<<<1, 64, 0, stream>>>(w4, b3_, R, WT);
  k_conv1<<<dim3(1, 64, 16), dim3(64, 4), 0, stream>>>(x, w1, b1_, h1e);
  k_conv2<<<dim3(1, 64, 32), dim3(64, 4), 0, stream>>>(h1e, w2, b2_, h2);
  k_deconv3<<<dim3(1, 64, 16), dim3(64, 4), 0, stream>>>(h2, w3, b3_, h3c);
  k_out_rows<<<dim3(511, 64), 256, 0, stream>>>(h3c, b4_, R, WT, out);
  k_out_border<<<dim3(34, 64), 256, 0, stream>>>(h3c, w4, b4_, b3_, out);
}

// Round 4
// 472.278 us; speedup vs baseline: 1.4374x; 1.0194x over previous
//
#include <hip/hip_runtime.h>

#define PLANE 1042441      // 1021*1021
#define S1 255             // h1 even-grid / h3 core spatial
#define S2 253             // h2 spatial
#define S1S1 65025
#define S2S2 64009
#define NOUT 66716224      // 8*8*1021*1021

// ws layout (floats): h1e[4161600] | h2[8193152] | h3c[4161600] | R[32] | WT[768]

// R[co*4+pc] = sum_ci relu(b3[ci]) * sum_{off-core taps for pc} w4[co][ci][jy][jx]
// WT[(co*8+ci)*12] = packed w4: [w00,w02,w20,w22, w01,w21,w10,w12, w11,0,0,0]
__global__ void k_setup(const float* __restrict__ w4, const float* __restrict__ b3_,
                        float* __restrict__ R, float* __restrict__ WT) {
  int t = threadIdx.x;
  if (t < 32) {
    int co = t >> 2, pc = t & 3;
    float s = 0.f;
    for (int ci = 0; ci < 8; ++ci) {
      float r3 = fmaxf(b3_[ci], 0.f);
      float wsum = 0.f;
      for (int jy = 0; jy < 3; ++jy)
        for (int jx = 0; jx < 3; ++jx) {
          bool cy = (pc & 2) ? (jy == 1) : (jy != 1);
          bool cx = (pc & 1) ? (jx == 1) : (jx != 1);
          if (!(cy && cx)) wsum += w4[(co * 8 + ci) * 9 + jy * 3 + jx];
        }
      s += r3 * wsum;
    }
    R[t] = s;
  }
  {
    int co = t >> 3, ci = t & 7;
    const float* w = w4 + (co * 8 + ci) * 9;
    float* d = WT + (co * 8 + ci) * 12;
    d[0] = w[0]; d[1] = w[2]; d[2] = w[6]; d[3] = w[8];
    d[4] = w[1]; d[5] = w[7]; d[6] = w[3]; d[7] = w[5];
    d[8] = w[4]; d[9] = 0.f; d[10] = 0.f; d[11] = 0.f;
  }
}

// conv1: each thread computes 4 outputs (t0..t0+3) x 4 co (cog..cog+3).
__global__ __launch_bounds__(256) void k_conv1(const float* __restrict__ x,
    const float* __restrict__ w1, const float* __restrict__ b1_, float* __restrict__ h1e) {
  int tx = threadIdx.x;                      // 0..63
  int t0 = tx * 4;                           // output col base, 0..252
  int m = blockIdx.y * 4 + threadIdx.y;      // output row
  if (m >= S1) return;
  int zb = blockIdx.z;                       // n*2 + g
  int n = zb >> 1, cog = (zb & 1) * 4;

  float acc[4][4];
#pragma unroll
  for (int cc = 0; cc < 4; ++cc) {
    float b = b1_[cog + cc];
#pragma unroll
    for (int p = 0; p < 4; ++p) acc[cc][p] = b;
  }

  const float* xn = x + (size_t)n * 3 * PLANE;
  int b0 = 4 * t0;                           // x col base = 16*tx, <= 1008
  int o7 = b0 + 14 <= 1020 ? b0 + 14 : 1020;
  int o8 = b0 + 16 <= 1020 ? b0 + 16 : 1020;

#pragma unroll
  for (int ci = 0; ci < 3; ++ci) {
#pragma unroll
    for (int ky = 0; ky < 3; ++ky) {
      const float* xr = xn + ci * PLANE + (size_t)(4 * m + 2 * ky) * 1021u;
      float v[9];
      v[0] = xr[b0];      v[1] = xr[b0 + 2];  v[2] = xr[b0 + 4];
      v[3] = xr[b0 + 6];  v[4] = xr[b0 + 8];  v[5] = xr[b0 + 10];
      v[6] = xr[b0 + 12]; v[7] = xr[o7];      v[8] = xr[o8];
#pragma unroll
      for (int cc = 0; cc < 4; ++cc) {
        const float* w = w1 + (cog + cc) * 27 + ci * 9 + ky * 3;
        float w0 = w[0], w1v = w[1], w2v = w[2];
#pragma unroll
        for (int p = 0; p < 4; ++p)
          acc[cc][p] = fmaf(v[2 * p], w0, fmaf(v[2 * p + 1], w1v, fmaf(v[2 * p + 2], w2v, acc[cc][p])));
      }
    }
  }

#pragma unroll
  for (int cc = 0; cc < 4; ++cc) {
    float* op = h1e + ((size_t)(n * 8 + cog + cc) * S1 + m) * S1 + t0;
#pragma unroll
    for (int p = 0; p < 4; ++p)
      if (t0 + p < S1) op[p] = fmaxf(acc[cc][p], 0.f);
  }
}

// h2: 4 pixels x 8 co per thread (was 4 co). float4 row-segment loads.
// h1e read multiplicity over co halves; loads/output 9 -> 4.5.
__global__ __launch_bounds__(256) void k_conv2(const float* __restrict__ h1e,
    const float* __restrict__ w2, const float* __restrict__ b2_, float* __restrict__ h2) {
  int v0 = threadIdx.x * 4;                  // 0..252
  int u = blockIdx.y * 4 + threadIdx.y;
  int zb = blockIdx.z;                       // n*2 + g
  int n = zb >> 1, cog = (zb & 1) * 8;
  if (u >= S2) return;
  float acc[8][4];
#pragma unroll
  for (int cc = 0; cc < 8; ++cc) {
    float b = b2_[cog + cc];
#pragma unroll
    for (int p = 0; p < 4; ++p) acc[cc][p] = b;
  }
  const float* hn = h1e + (size_t)n * 8 * S1S1;
  for (int ci = 0; ci < 8; ++ci) {
    const float* hc = hn + ci * S1S1;
#pragma unroll
    for (int ky = 0; ky < 3; ++ky) {
      const float* hr = hc + (u + ky) * S1 + v0;
      float4 r4 = *(const float4*)hr;        // 4B-aligned float4: ok on gfx950
      float rr[6] = {r4.x, r4.y, r4.z, r4.w, hr[4], hr[5]};  // overread feeds masked outputs only
#pragma unroll
      for (int cc = 0; cc < 8; ++cc) {
        const float* w = w2 + (cog + cc) * 72 + ci * 9 + ky * 3;
        float w0 = w[0], w1 = w[1], w2v = w[2];
#pragma unroll
        for (int p = 0; p < 4; ++p)
          acc[cc][p] = fmaf(rr[p], w0, fmaf(rr[p + 1], w1, fmaf(rr[p + 2], w2v, acc[cc][p])));
      }
    }
  }
#pragma unroll
  for (int cc = 0; cc < 8; ++cc) {
    float* op = h2 + ((size_t)(n * 16 + cog + cc) * S2 + u) * S2 + v0;
    if (v0 + 3 < S2) {
      *(float4*)op = make_float4(fmaxf(acc[cc][0], 0.f), fmaxf(acc[cc][1], 0.f),
                                 fmaxf(acc[cc][2], 0.f), fmaxf(acc[cc][3], 0.f));
    } else {
#pragma unroll
      for (int p = 0; p < 4; ++p)
        if (v0 + p < S2) op[p] = fmaxf(acc[cc][p], 0.f);
    }
  }
}

// h3core: 4 pixels x 8 co per thread (was 4 co). float4 row-segment loads.
// h2 read multiplicity over co groups eliminated; loads/output 18 -> 9.
__global__ __launch_bounds__(256) void k_deconv3(const float* __restrict__ h2,
    const float* __restrict__ w3, const float* __restrict__ b3_, float* __restrict__ h3c) {
  int r0 = threadIdx.x * 4;                  // 0..252
  int q = blockIdx.y * 4 + threadIdx.y;
  int n = blockIdx.z;
  if (q >= S1) return;
  float acc[8][4];
#pragma unroll
  for (int cc = 0; cc < 8; ++cc) {
    float b = b3_[cc];
#pragma unroll
    for (int p = 0; p < 4; ++p) acc[cc][p] = b;
  }
  const float* hn = h2 + (size_t)n * 16 * S2S2;
  bool inner = (r0 >= 4 && r0 <= 248);
  for (int ci = 0; ci < 16; ++ci) {
    const float* hc = hn + ci * S2S2;
#pragma unroll
    for (int jy = 0; jy < 3; ++jy) {
      int a = q - jy;
      if ((unsigned)a > 252u) continue;
      const float* hr = hc + a * S2 + (r0 - 2);
      float rr[6];
      if (inner) {
        float4 r4 = *(const float4*)hr;      // cols r0-2..r0+1, all in [2,249]
        rr[0] = r4.x; rr[1] = r4.y; rr[2] = r4.z; rr[3] = r4.w;
        rr[4] = hr[4]; rr[5] = hr[5];
      } else {
#pragma unroll
        for (int q2 = 0; q2 < 6; ++q2) {
          int col = r0 - 2 + q2;
          rr[q2] = ((unsigned)col <= 252u) ? hr[q2] : 0.f;
        }
      }
#pragma unroll
      for (int cc = 0; cc < 8; ++cc) {
        const float* w = w3 + (cc * 16 + ci) * 9 + jy * 3;
        float w0 = w[0], w1 = w[1], w2v = w[2];
        // b = r0+p-jx -> rr[p-jx+2]
#pragma unroll
        for (int p = 0; p < 4; ++p)
          acc[cc][p] = fmaf(rr[p + 2], w0, fmaf(rr[p + 1], w1, fmaf(rr[p], w2v, acc[cc][p])));
      }
    }
  }
#pragma unroll
  for (int cc = 0; cc < 8; ++cc) {
    float* op = h3c + ((size_t)(n * 8 + cc) * S1 + q) * S1 + r0;
    if (r0 + 3 < S1) {
      *(float4*)op = make_float4(fmaxf(acc[cc][0], 0.f), fmaxf(acc[cc][1], 0.f),
                                 fmaxf(acc[cc][2], 0.f), fmaxf(acc[cc][3], 0.f));
    } else {
#pragma unroll
      for (int p = 0; p < 4; ++p)
        if (r0 + p < S1) op[p] = fmaxf(acc[cc][p], 0.f);
    }
  }
}

// General (border) per-element output value.
__device__ __forceinline__ float general_val(unsigned idx, const float* __restrict__ h3c,
    const float* __restrict__ w4, const float* __restrict__ b4_, const float* __restrict__ b3_) {
  unsigned z = idx / PLANE;
  unsigned rem = idx - z * PLANE;
  unsigned y = rem / 1021u;
  unsigned x = rem - y * 1021u;
  int co = z & 7;
  float acc = b4_[co];
  if ((y | x) & 1u) return acc;
  int py = y >> 1, px = x >> 1;
  const float* hn = h3c + (size_t)(z >> 3) * 8 * S1S1;
  const float* wp = w4 + co * 72;
  for (int ci = 0; ci < 8; ++ci) {
    float r3 = fmaxf(b3_[ci], 0.f);
    const float* hcc = hn + ci * S1S1;
#pragma unroll
    for (int jy = 0; jy < 3; ++jy) {
      int a = py - jy;
#pragma unroll
      for (int jx = 0; jx < 3; ++jx) {
        int b = px - jx;
        float h;
        if ((unsigned)a > 508u || (unsigned)b > 508u) h = 0.f;
        else if (((a | b) & 1) == 0) h = hcc[(a >> 1) * S1 + (b >> 1)];
        else h = r3;
        acc = fmaf(h, wp[ci * 9 + jy * 3 + jx], acc);
      }
    }
  }
  return acc;
}

// Row-pair kernel: block = (even row ye=2*bx, odd row ye+1) of plane z.
__global__ __launch_bounds__(256) void k_out_rows(const float* __restrict__ h3c,
    const float* __restrict__ b4_, const float* __restrict__ R,
    const float* __restrict__ WT, float* __restrict__ out) {
  int t = threadIdx.x;
  int ye = blockIdx.x * 2;                   // even row, 0..1020
  int z = blockIdx.y;                        // n*8+co
  int co = z & 7;
  float b4f = b4_[co];
  float* orow = out + (size_t)z * PLANE + (size_t)ye * 1021u;

  // odd row ye+1: pure constant
  if (ye < 1020) {
    float* orow1 = orow + 1021;
    if (t < 255) *(float4*)(orow1 + 4 * t) = make_float4(b4f, b4f, b4f, b4f);
    else orow1[1020] = b4f;
  }

  // even row: interior only (border kernel covers ye in {0,2,1018,1020},
  // and x in {0..3, 1016..1020} of other even rows)
  if (ye < 4 || ye > 1016) return;
  if (t == 0 || t >= 254) return;
  unsigned py = (unsigned)ye >> 1;
  const float* hn = h3c + (size_t)(z >> 3) * 8 * S1S1;
  const float* wt = WT + co * 96;
  int col0 = t - 1;                          // cols col0, col0+1 feed px=2t (even), px=2t+1 (odd)
  float vE = 0.f, vO = 0.f, rE, rO;
  if ((py & 1u) == 0) {
    unsigned i = py >> 1;                    // rows i-1, i of h3c
    const float* hp = hn + (i - 1) * S1 + col0;
#pragma unroll
    for (int ci = 0; ci < 8; ++ci) {
      const float* p = hp + ci * S1S1;
      float m00 = p[0], m01 = p[1], m10 = p[S1], m11 = p[S1 + 1];
      float4 A = *(const float4*)(wt + ci * 12);
      float4 B = *(const float4*)(wt + ci * 12 + 4);
      vE = fmaf(m11, A.x, fmaf(m10, A.y, fmaf(m01, A.z, fmaf(m00, A.w, vE))));
      vO = fmaf(m11, B.x, fmaf(m01, B.y, vO));
    }
    rE = b4f + R[co * 4 + 0] + vE;
    rO = b4f + R[co * 4 + 1] + vO;
  } else {
    unsigned a = py >> 1;                    // single row a of h3c
    const float* hp = hn + a * S1 + col0;
#pragma unroll
    for (int ci = 0; ci < 8; ++ci) {
      const float* p = hp + ci * S1S1;
      float n0 = p[0], n1 = p[1];
      float4 B = *(const float4*)(wt + ci * 12 + 4);
      float w11 = wt[ci * 12 + 8];
      vE = fmaf(n1, B.z, fmaf(n0, B.w, vE));
      vO = fmaf(n1, w11, vO);
    }
    rE = b4f + R[co * 4 + 2] + vE;
    rO = b4f + R[co * 4 + 3] + vO;
  }
  *(float4*)(orow + 4 * t) = make_float4(rE, b4f, rO, b4f);
}

// Border kernel: even-row x-borders (x in {0,1,2,3} u {1016..1020}, y=4..1016 even: 507 rows)
// and the 4 even border rows (y in {0,2,1018,1020}) in full. ~2% of output.
__global__ __launch_bounds__(256) void k_out_border(const float* __restrict__ h3c,
    const float* __restrict__ w4, const float* __restrict__ b4_,
    const float* __restrict__ b3_, float* __restrict__ out) {
  int z = blockIdx.y;
  unsigned y, x;
  if (blockIdx.x < 18) {                     // x-border: 507*9 = 4563 elements
    unsigned e = blockIdx.x * 256 + threadIdx.x;
    if (e >= 507u * 9u) return;
    unsigned r = e / 9u, c = e - r * 9u;
    y = 4u + 2u * r;
    x = (c < 4u) ? c : (1012u + c);          // c=4..8 -> 1016..1020
  } else {                                   // y-border rows: 4*1021 = 4084 elements
    unsigned e2 = (blockIdx.x - 18) * 256 + threadIdx.x;
    if (e2 >= 4u * 1021u) return;
    unsigned rr = e2 / 1021u;
    y = (rr < 2u) ? 2u * rr : (1014u + 2u * rr);   // 0,2,1018,1020
    x = e2 - rr * 1021u;
  }
  unsigned idx = (unsigned)z * PLANE + y * 1021u + x;
  out[idx] = general_val(idx, h3c, w4, b4_, b3_);
}

extern "C" void kernel_launch(void* const* d_in, const int* in_sizes, int n_in,
                              void* d_out, int out_size, void* d_ws, size_t ws_size,
                              hipStream_t stream) {
  const float* x   = (const float*)d_in[0];
  const float* w1  = (const float*)d_in[1];
  const float* b1_ = (const float*)d_in[2];
  const float* w2  = (const float*)d_in[3];
  const float* b2_ = (const float*)d_in[4];
  const float* w3  = (const float*)d_in[5];
  const float* b3_ = (const float*)d_in[6];
  const float* w4  = (const float*)d_in[7];
  const float* b4_ = (const float*)d_in[8];
  float* out = (float*)d_out;

  float* h1e = (float*)d_ws;
  float* h2  = h1e + (size_t)8 * 8 * S1S1;
  float* h3c = h2 + (size_t)8 * 16 * S2S2;
  float* R   = h3c + (size_t)8 * 8 * S1S1;
  float* WT  = R + 32;

  k_setup<<<1, 64, 0, stream>>>(w4, b3_, R, WT);
  k_conv1<<<dim3(1, 64, 16), dim3(64, 4), 0, stream>>>(x, w1, b1_, h1e);
  k_conv2<<<dim3(1, 64, 16), dim3(64, 4), 0, stream>>>(h1e, w2, b2_, h2);
  k_deconv3<<<dim3(1, 64, 8), dim3(64, 4), 0, stream>>>(h2, w3, b3_, h3c);
  k_out_rows<<<dim3(511, 64), 256, 0, stream>>>(h3c, b4_, R, WT, out);
  k_out_border<<<dim3(34, 64), 256, 0, stream>>>(h3c, w4, b4_, b3_, out);
}

// Round 5
// 462.760 us; speedup vs baseline: 1.4670x; 1.0206x over previous
//
#include <hip/hip_runtime.h>

#define PLANE 1042441      // 1021*1021
#define S1 255             // h1 even-grid / h3 core spatial
#define S2 253             // h2 spatial
#define S1S1 65025
#define S2S2 64009
#define NOUT 66716224      // 8*8*1021*1021

// ws layout (floats): h1e[4161600] | h2[8193152] | h3c[4161600] | R[32] | WT[768]

// R[co*4+pc] = sum_ci relu(b3[ci]) * sum_{off-core taps for pc} w4[co][ci][jy][jx]
// WT[(co*8+ci)*12] = packed w4: [w00,w02,w20,w22, w01,w21,w10,w12, w11,0,0,0]
__global__ void k_setup(const float* __restrict__ w4, const float* __restrict__ b3_,
                        float* __restrict__ R, float* __restrict__ WT) {
  int t = threadIdx.x;
  if (t < 32) {
    int co = t >> 2, pc = t & 3;
    float s = 0.f;
    for (int ci = 0; ci < 8; ++ci) {
      float r3 = fmaxf(b3_[ci], 0.f);
      float wsum = 0.f;
      for (int jy = 0; jy < 3; ++jy)
        for (int jx = 0; jx < 3; ++jx) {
          bool cy = (pc & 2) ? (jy == 1) : (jy != 1);
          bool cx = (pc & 1) ? (jx == 1) : (jx != 1);
          if (!(cy && cx)) wsum += w4[(co * 8 + ci) * 9 + jy * 3 + jx];
        }
      s += r3 * wsum;
    }
    R[t] = s;
  }
  {
    int co = t >> 3, ci = t & 7;
    const float* w = w4 + (co * 8 + ci) * 9;
    float* d = WT + (co * 8 + ci) * 12;
    d[0] = w[0]; d[1] = w[2]; d[2] = w[6]; d[3] = w[8];
    d[4] = w[1]; d[5] = w[7]; d[6] = w[3]; d[7] = w[5];
    d[8] = w[4]; d[9] = 0.f; d[10] = 0.f; d[11] = 0.f;
  }
}

// conv1 v3: single pass over x. Each thread: 4 outputs x ALL 8 co (32 acc).
// Row segment loaded as 3 float4 + 3 scalars (cols b0..b0+16 even used).
__global__ __launch_bounds__(256) void k_conv1(const float* __restrict__ x,
    const float* __restrict__ w1, const float* __restrict__ b1_, float* __restrict__ h1e) {
  int tx = threadIdx.x;                      // 0..63
  int t0 = tx * 4;                           // output col base, 0..252
  int m = blockIdx.y * 4 + threadIdx.y;      // output row
  if (m >= S1) return;                       // wave-uniform
  int n = blockIdx.z;

  float acc[8][4];
#pragma unroll
  for (int cc = 0; cc < 8; ++cc) {
    float b = b1_[cc];
#pragma unroll
    for (int p = 0; p < 4; ++p) acc[cc][p] = b;
  }

  const float* xn = x + (size_t)n * 3 * PLANE;
  int b0 = 16 * tx;                          // x col base, <= 1008
  // v[7]=col b0+14, v[8]=col b0+16 only feed output p=3 (masked for tx==63) -> clamp.
  int o7 = b0 + 14 <= 1020 ? b0 + 14 : 1020;
  int o8 = b0 + 16 <= 1020 ? b0 + 16 : 1020;

#pragma unroll
  for (int ci = 0; ci < 3; ++ci) {
#pragma unroll
    for (int ky = 0; ky < 3; ++ky) {
      const float* xr = xn + ci * PLANE + (size_t)(4 * m + 2 * ky) * 1021u;
      float4 qa = *(const float4*)(xr + b0);       // cols b0..b0+3   (<=1011)
      float4 qb = *(const float4*)(xr + b0 + 4);   // cols b0+4..b0+7 (<=1015)
      float4 qc = *(const float4*)(xr + b0 + 8);   // cols b0+8..b0+11(<=1019)
      float v[9];
      v[0] = qa.x; v[1] = qa.z; v[2] = qb.x; v[3] = qb.z;
      v[4] = qc.x; v[5] = qc.z;
      v[6] = xr[b0 + 12];                          // col <=1020
      v[7] = xr[o7]; v[8] = xr[o8];
#pragma unroll
      for (int cc = 0; cc < 8; ++cc) {
        const float* w = w1 + cc * 27 + ci * 9 + ky * 3;
        float w0 = w[0], w1v = w[1], w2v = w[2];
        // output t0+p taps x cols b0+4p+2kx -> v[2p+kx]
#pragma unroll
        for (int p = 0; p < 4; ++p)
          acc[cc][p] = fmaf(v[2 * p], w0, fmaf(v[2 * p + 1], w1v, fmaf(v[2 * p + 2], w2v, acc[cc][p])));
      }
    }
  }

#pragma unroll
  for (int cc = 0; cc < 8; ++cc) {
    float* op = h1e + ((size_t)(n * 8 + cc) * S1 + m) * S1 + t0;
    if (t0 + 3 < S1) {
      *(float4*)op = make_float4(fmaxf(acc[cc][0], 0.f), fmaxf(acc[cc][1], 0.f),
                                 fmaxf(acc[cc][2], 0.f), fmaxf(acc[cc][3], 0.f));
    } else {
#pragma unroll
      for (int p = 0; p < 4; ++p)
        if (t0 + p < S1) op[p] = fmaxf(acc[cc][p], 0.f);
    }
  }
}

// h2: 4 pixels x 8 co per thread. float4 row-segment loads.
__global__ __launch_bounds__(256) void k_conv2(const float* __restrict__ h1e,
    const float* __restrict__ w2, const float* __restrict__ b2_, float* __restrict__ h2) {
  int v0 = threadIdx.x * 4;                  // 0..252
  int u = blockIdx.y * 4 + threadIdx.y;
  int zb = blockIdx.z;                       // n*2 + g
  int n = zb >> 1, cog = (zb & 1) * 8;
  if (u >= S2) return;
  float acc[8][4];
#pragma unroll
  for (int cc = 0; cc < 8; ++cc) {
    float b = b2_[cog + cc];
#pragma unroll
    for (int p = 0; p < 4; ++p) acc[cc][p] = b;
  }
  const float* hn = h1e + (size_t)n * 8 * S1S1;
  for (int ci = 0; ci < 8; ++ci) {
    const float* hc = hn + ci * S1S1;
#pragma unroll
    for (int ky = 0; ky < 3; ++ky) {
      const float* hr = hc + (u + ky) * S1 + v0;
      float4 r4 = *(const float4*)hr;
      float rr[6] = {r4.x, r4.y, r4.z, r4.w, hr[4], hr[5]};
#pragma unroll
      for (int cc = 0; cc < 8; ++cc) {
        const float* w = w2 + (cog + cc) * 72 + ci * 9 + ky * 3;
        float w0 = w[0], w1 = w[1], w2v = w[2];
#pragma unroll
        for (int p = 0; p < 4; ++p)
          acc[cc][p] = fmaf(rr[p], w0, fmaf(rr[p + 1], w1, fmaf(rr[p + 2], w2v, acc[cc][p])));
      }
    }
  }
#pragma unroll
  for (int cc = 0; cc < 8; ++cc) {
    float* op = h2 + ((size_t)(n * 16 + cog + cc) * S2 + u) * S2 + v0;
    if (v0 + 3 < S2) {
      *(float4*)op = make_float4(fmaxf(acc[cc][0], 0.f), fmaxf(acc[cc][1], 0.f),
                                 fmaxf(acc[cc][2], 0.f), fmaxf(acc[cc][3], 0.f));
    } else {
#pragma unroll
      for (int p = 0; p < 4; ++p)
        if (v0 + p < S2) op[p] = fmaxf(acc[cc][p], 0.f);
    }
  }
}

// h3core: 4 pixels x 8 co per thread. float4 row-segment loads.
__global__ __launch_bounds__(256) void k_deconv3(const float* __restrict__ h2,
    const float* __restrict__ w3, const float* __restrict__ b3_, float* __restrict__ h3c) {
  int r0 = threadIdx.x * 4;                  // 0..252
  int q = blockIdx.y * 4 + threadIdx.y;
  int n = blockIdx.z;
  if (q >= S1) return;
  float acc[8][4];
#pragma unroll
  for (int cc = 0; cc < 8; ++cc) {
    float b = b3_[cc];
#pragma unroll
    for (int p = 0; p < 4; ++p) acc[cc][p] = b;
  }
  const float* hn = h2 + (size_t)n * 16 * S2S2;
  bool inner = (r0 >= 4 && r0 <= 248);
  for (int ci = 0; ci < 16; ++ci) {
    const float* hc = hn + ci * S2S2;
#pragma unroll
    for (int jy = 0; jy < 3; ++jy) {
      int a = q - jy;
      if ((unsigned)a > 252u) continue;
      const float* hr = hc + a * S2 + (r0 - 2);
      float rr[6];
      if (inner) {
        float4 r4 = *(const float4*)hr;
        rr[0] = r4.x; rr[1] = r4.y; rr[2] = r4.z; rr[3] = r4.w;
        rr[4] = hr[4]; rr[5] = hr[5];
      } else {
#pragma unroll
        for (int q2 = 0; q2 < 6; ++q2) {
          int col = r0 - 2 + q2;
          rr[q2] = ((unsigned)col <= 252u) ? hr[q2] : 0.f;
        }
      }
#pragma unroll
      for (int cc = 0; cc < 8; ++cc) {
        const float* w = w3 + (cc * 16 + ci) * 9 + jy * 3;
        float w0 = w[0], w1 = w[1], w2v = w[2];
#pragma unroll
        for (int p = 0; p < 4; ++p)
          acc[cc][p] = fmaf(rr[p + 2], w0, fmaf(rr[p + 1], w1, fmaf(rr[p], w2v, acc[cc][p])));
      }
    }
  }
#pragma unroll
  for (int cc = 0; cc < 8; ++cc) {
    float* op = h3c + ((size_t)(n * 8 + cc) * S1 + q) * S1 + r0;
    if (r0 + 3 < S1) {
      *(float4*)op = make_float4(fmaxf(acc[cc][0], 0.f), fmaxf(acc[cc][1], 0.f),
                                 fmaxf(acc[cc][2], 0.f), fmaxf(acc[cc][3], 0.f));
    } else {
#pragma unroll
      for (int p = 0; p < 4; ++p)
        if (r0 + p < S1) op[p] = fmaxf(acc[cc][p], 0.f);
    }
  }
}

// General (border) per-element output value.
__device__ __forceinline__ float general_val(unsigned idx, const float* __restrict__ h3c,
    const float* __restrict__ w4, const float* __restrict__ b4_, const float* __restrict__ b3_) {
  unsigned z = idx / PLANE;
  unsigned rem = idx - z * PLANE;
  unsigned y = rem / 1021u;
  unsigned x = rem - y * 1021u;
  int co = z & 7;
  float acc = b4_[co];
  if ((y | x) & 1u) return acc;
  int py = y >> 1, px = x >> 1;
  const float* hn = h3c + (size_t)(z >> 3) * 8 * S1S1;
  const float* wp = w4 + co * 72;
  for (int ci = 0; ci < 8; ++ci) {
    float r3 = fmaxf(b3_[ci], 0.f);
    const float* hcc = hn + ci * S1S1;
#pragma unroll
    for (int jy = 0; jy < 3; ++jy) {
      int a = py - jy;
#pragma unroll
      for (int jx = 0; jx < 3; ++jx) {
        int b = px - jx;
        float h;
        if ((unsigned)a > 508u || (unsigned)b > 508u) h = 0.f;
        else if (((a | b) & 1) == 0) h = hcc[(a >> 1) * S1 + (b >> 1)];
        else h = r3;
        acc = fmaf(h, wp[ci * 9 + jy * 3 + jx], acc);
      }
    }
  }
  return acc;
}

// Row-pair kernel: block = (even row ye=2*bx, odd row ye+1) of plane z.
__global__ __launch_bounds__(256) void k_out_rows(const float* __restrict__ h3c,
    const float* __restrict__ b4_, const float* __restrict__ R,
    const float* __restrict__ WT, float* __restrict__ out) {
  int t = threadIdx.x;
  int ye = blockIdx.x * 2;                   // even row, 0..1020
  int z = blockIdx.y;                        // n*8+co
  int co = z & 7;
  float b4f = b4_[co];
  float* orow = out + (size_t)z * PLANE + (size_t)ye * 1021u;

  // odd row ye+1: pure constant
  if (ye < 1020) {
    float* orow1 = orow + 1021;
    if (t < 255) *(float4*)(orow1 + 4 * t) = make_float4(b4f, b4f, b4f, b4f);
    else orow1[1020] = b4f;
  }

  // even row: interior only (border kernel covers ye in {0,2,1018,1020},
  // and x in {0..3, 1016..1020} of other even rows)
  if (ye < 4 || ye > 1016) return;
  if (t == 0 || t >= 254) return;
  unsigned py = (unsigned)ye >> 1;
  const float* hn = h3c + (size_t)(z >> 3) * 8 * S1S1;
  const float* wt = WT + co * 96;
  int col0 = t - 1;                          // cols col0, col0+1 feed px=2t (even), px=2t+1 (odd)
  float vE = 0.f, vO = 0.f, rE, rO;
  if ((py & 1u) == 0) {
    unsigned i = py >> 1;                    // rows i-1, i of h3c
    const float* hp = hn + (i - 1) * S1 + col0;
#pragma unroll
    for (int ci = 0; ci < 8; ++ci) {
      const float* p = hp + ci * S1S1;
      float m00 = p[0], m01 = p[1], m10 = p[S1], m11 = p[S1 + 1];
      float4 A = *(const float4*)(wt + ci * 12);
      float4 B = *(const float4*)(wt + ci * 12 + 4);
      vE = fmaf(m11, A.x, fmaf(m10, A.y, fmaf(m01, A.z, fmaf(m00, A.w, vE))));
      vO = fmaf(m11, B.x, fmaf(m01, B.y, vO));
    }
    rE = b4f + R[co * 4 + 0] + vE;
    rO = b4f + R[co * 4 + 1] + vO;
  } else {
    unsigned a = py >> 1;                    // single row a of h3c
    const float* hp = hn + a * S1 + col0;
#pragma unroll
    for (int ci = 0; ci < 8; ++ci) {
      const float* p = hp + ci * S1S1;
      float n0 = p[0], n1 = p[1];
      float4 B = *(const float4*)(wt + ci * 12 + 4);
      float w11 = wt[ci * 12 + 8];
      vE = fmaf(n1, B.z, fmaf(n0, B.w, vE));
      vO = fmaf(n1, w11, vO);
    }
    rE = b4f + R[co * 4 + 2] + vE;
    rO = b4f + R[co * 4 + 3] + vO;
  }
  *(float4*)(orow + 4 * t) = make_float4(rE, b4f, rO, b4f);
}

// Border kernel: even-row x-borders (x in {0,1,2,3} u {1016..1020}, y=4..1016 even: 507 rows)
// and the 4 even border rows (y in {0,2,1018,1020}) in full. ~2% of output.
__global__ __launch_bounds__(256) void k_out_border(const float* __restrict__ h3c,
    const float* __restrict__ w4, const float* __restrict__ b4_,
    const float* __restrict__ b3_, float* __restrict__ out) {
  int z = blockIdx.y;
  unsigned y, x;
  if (blockIdx.x < 18) {                     // x-border: 507*9 = 4563 elements
    unsigned e = blockIdx.x * 256 + threadIdx.x;
    if (e >= 507u * 9u) return;
    unsigned r = e / 9u, c = e - r * 9u;
    y = 4u + 2u * r;
    x = (c < 4u) ? c : (1012u + c);          // c=4..8 -> 1016..1020
  } else {                                   // y-border rows: 4*1021 = 4084 elements
    unsigned e2 = (blockIdx.x - 18) * 256 + threadIdx.x;
    if (e2 >= 4u * 1021u) return;
    unsigned rr = e2 / 1021u;
    y = (rr < 2u) ? 2u * rr : (1014u + 2u * rr);   // 0,2,1018,1020
    x = e2 - rr * 1021u;
  }
  unsigned idx = (unsigned)z * PLANE + y * 1021u + x;
  out[idx] = general_val(idx, h3c, w4, b4_, b3_);
}

extern "C" void kernel_launch(void* const* d_in, const int* in_sizes, int n_in,
                              void* d_out, int out_size, void* d_ws, size_t ws_size,
                              hipStream_t stream) {
  const float* x   = (const float*)d_in[0];
  const float* w1  = (const float*)d_in[1];
  const float* b1_ = (const float*)d_in[2];
  const float* w2  = (const float*)d_in[3];
  const float* b2_ = (const float*)d_in[4];
  const float* w3  = (const float*)d_in[5];
  const float* b3_ = (const float*)d_in[6];
  const float* w4  = (const float*)d_in[7];
  const float* b4_ = (const float*)d_in[8];
  float* out = (float*)d_out;

  float* h1e = (float*)d_ws;
  float* h2  = h1e + (size_t)8 * 8 * S1S1;
  float* h3c = h2 + (size_t)8 * 16 * S2S2;
  float* R   = h3c + (size_t)8 * 8 * S1S1;
  float* WT  = R + 32;

  k_setup<<<1, 64, 0, stream>>>(w4, b3_, R, WT);
  k_conv1<<<dim3(1, 64, 8), dim3(64, 4), 0, stream>>>(x, w1, b1_, h1e);
  k_conv2<<<dim3(1, 64, 16), dim3(64, 4), 0, stream>>>(h1e, w2, b2_, h2);
  k_deconv3<<<dim3(1, 64, 8), dim3(64, 4), 0, stream>>>(h2, w3, b3_, h3c);
  k_out_rows<<<dim3(511, 64), 256, 0, stream>>>(h3c, b4_, R, WT, out);
  k_out_border<<<dim3(34, 64), 256, 0, stream>>>(h3c, w4, b4_, b3_, out);
}